// Round 9
// baseline (243.988 us; speedup 1.0000x reference)
//
#include <hip/hip_runtime.h>

#define NUM_ROWS 500000
#define TERMS 164
#define KSTEPS 6                       // 6 * 32 = 192 k-slots (164 terms + bias@164 + pad)
#define NFRAG (KSTEPS * 4)             // 24 weight fragments, each 64 lanes x uint4
#define NITER ((NUM_ROWS + 63) / 64)   // 7813 (last iter: 32 rows)
#define SOSTRIDE 68                    // padded row stride (words) for transpose buf
#define WAVE_BYTES 4608                // per-wave LDS: max(sT 4096, sO 4352) + pad

typedef __attribute__((ext_vector_type(8))) short bf16x8;
typedef __attribute__((ext_vector_type(4))) float f32x4;
typedef __attribute__((ext_vector_type(4))) unsigned int uint4v;

// ---------------------------------------------------------------------------
// Compile-time replica of the reference exponent-table construction
// (verified round 1: term order matches numpy meshgrid/.T/reshape exactly).
// ---------------------------------------------------------------------------
struct ETab { int e[192][8]; int n; };

constexpr ETab make_et() {
    ETab T{};
    for (int i = 0; i < 192; ++i)
        for (int f = 0; f < 8; ++f) T.e[i][f] = 0;
    T.n = 0;
    for (int a = 0; a <= 3; ++a)                       // e7
     for (int b = 0; a + b <= 3; ++b)                  // e6
      for (int c = 0; a + b + c <= 3; ++c)             // e5
       for (int d = 0; a + b + c + d <= 3; ++d)        // e4
        for (int e_ = 0; a + b + c + d + e_ <= 3; ++e_)            // e3
         for (int f_ = 0; a + b + c + d + e_ + f_ <= 3; ++f_)      // e2
          for (int g = 0; a + b + c + d + e_ + f_ + g <= 3; ++g)   // e0
           for (int h = 0; a + b + c + d + e_ + f_ + g + h <= 3; ++h) { // e1
               int s = a + b + c + d + e_ + f_ + g + h;
               if (s >= 1) {
                   T.e[T.n][0] = g;  T.e[T.n][1] = h;
                   T.e[T.n][2] = f_; T.e[T.n][3] = e_;
                   T.e[T.n][4] = d;  T.e[T.n][5] = c;
                   T.e[T.n][6] = b;  T.e[T.n][7] = a;
                   ++T.n;
               }
           }
    return T;
}

static_assert(make_et().n == TERMS, "term count must be 164");
__device__ constexpr ETab ET = make_et();

// Manual RNE float->bf16 pack (verified rounds 1/3/4/6/7) — staging path.
__device__ __forceinline__ unsigned int pack2bf(float a, float b) {
    unsigned int ua = __float_as_uint(a), ub = __float_as_uint(b);
    ua = ua + 0x7fffu + ((ua >> 16) & 1u);
    ub = ub + 0x7fffu + ((ub >> 16) & 1u);
    return (ua >> 16) | (ub & 0xffff0000u);
}

// Hot-loop pack: single v_cvt_pk_bf16_f32 (src0 -> low16, src1 -> high16).
// No builtin on gfx950; inline asm per T12 recipe. Replaces 5 int-ops with 1.
__device__ __forceinline__ unsigned int pack2bf_fast(float a, float b) {
    unsigned int r;
    asm("v_cvt_pk_bf16_f32 %0, %1, %2" : "=v"(r) : "v"(a), "v"(b));
    return r;
}

// Basis term value; t is compile-time constant after unrolling, so ET loads
// and degree branches fold away (<=2 v_mul_f32 per term). Slot 164 is the
// bias slot: basis value 1.0 for every row (weight side carries bias[j]).
__device__ __forceinline__ float term_val(int t, const float (&p1)[8],
                                          const float (&p2)[8],
                                          const float (&p3)[8]) {
    if (t > TERMS) return 0.f;
    if (t == TERMS) return 1.f;
    float v = 1.f;
#pragma unroll
    for (int f = 0; f < 8; ++f) {
        const int d = ET.e[t][f];
        if (d == 1) v *= p1[f];
        else if (d == 2) v *= p2[f];
        else if (d == 3) v *= p3[f];
    }
    return v;
}

// Weight-side value for k-slot t of output column j (runtime t, staging only).
__device__ __forceinline__ float wval(const float* __restrict__ w,
                                      const float* __restrict__ b,
                                      int j, int t) {
    if (t < TERMS) return w[j * TERMS + t];
    if (t == TERMS) return b[j];
    return 0.f;
}

// ---------------------------------------------------------------------------
// Single fused kernel (round 9): weight A-fragments staged per block in LDS
// (index math identical to the verified pack_weights_kernel), removing the
// separate pack dispatch + its serialization in the graph.
//
// Compute identical to VERIFIED rounds 4/6/7/8 (A=weights, B=basis; absmax
// 0.25). acc[ct][q][r] = out[row rbase+q*16+m][col ct*16+kq*4+r].
// Round-7 lesson: plain __launch_bounds__(256) — the (256,4) variant forced
// 64 VGPRs vs a ~125-reg live set and spilled the accumulators to scratch.
// Grid 2048 (round-7 best); no x-prefetch (neutral-negative in round 8).
// sT/sO unioned per wave (disjoint live ranges; same-wave DS ordering).
// ---------------------------------------------------------------------------
__global__ __launch_bounds__(256) void poly_fused_kernel(
        const float* __restrict__ x, const float* __restrict__ weight,
        const float* __restrict__ bias, float* __restrict__ out) {
    __shared__ __align__(16) char smem[4 * WAVE_BYTES];   // 18 KiB
    __shared__ __align__(16) unsigned int sB[NFRAG * 256];// 24 KiB

    const int tid = threadIdx.x;

    // --- stage packed weight fragments (manual RNE pack, verified) ---
#pragma unroll 1
    for (int idx = tid; idx < NFRAG * 256; idx += 256) {
        int p = idx >> 8, lane8 = (idx >> 2) & 63, dw = idx & 3;
        int ks = p >> 2, ct = p & 3, kq8 = lane8 >> 4;
        int j  = (ct << 4) | (lane8 & 15);
        int t0 = ks * 32 + kq8 * 8 + dw * 2;
        sB[idx] = pack2bf(wval(weight, bias, j, t0), wval(weight, bias, j, t0 + 1));
    }
    __syncthreads();

    const int lane = tid & 63;
    const int wid  = tid >> 6;
    const int m    = lane & 15;
    const int kq   = lane >> 4;

    char* wbase = smem + wid * WAVE_BYTES;
    uint4v* sT = (uint4v*)wbase;        // [4 chunks][64 lanes], 4096 B
    float*  sO = (float*)wbase;         // [16 rows][68 words], 4352 B
    const uint4v* sB4 = (const uint4v*)sB;

    const int gw = blockIdx.x * 4 + wid;
    const int nw = gridDim.x * 4;

#pragma unroll 1
    for (int it = gw; it < NITER; it += nw) {
        const int rbase = it * 64;
        const int myrow = rbase + lane;

        float4 xa = {0.f, 0.f, 0.f, 0.f}, xb = {0.f, 0.f, 0.f, 0.f};
        if (myrow < NUM_ROWS) {
            const float4* xp = (const float4*)(x + (size_t)myrow * 8);
            xa = xp[0]; xb = xp[1];
        }
        float p1[8], p2[8], p3[8];
        p1[0] = xa.x; p1[1] = xa.y; p1[2] = xa.z; p1[3] = xa.w;
        p1[4] = xb.x; p1[5] = xb.y; p1[6] = xb.z; p1[7] = xb.w;
#pragma unroll
        for (int f = 0; f < 8; ++f) {
            p2[f] = p1[f] * p1[f];
            p3[f] = p2[f] * p1[f];
        }

        f32x4 acc[4][4];   // [ct][q] — 64 VGPRs, must stay in registers
#pragma unroll
        for (int ct = 0; ct < 4; ++ct)
#pragma unroll
            for (int q = 0; q < 4; ++q)
                acc[ct][q] = (f32x4){0.f, 0.f, 0.f, 0.f};

#pragma unroll
        for (int ks = 0; ks < KSTEPS; ++ks) {
            // --- my row's 32 terms for this ks, packed into 4 uint4 chunks ---
#pragma unroll
            for (int c = 0; c < 4; ++c) {
                uint4v ch;
#pragma unroll
                for (int d = 0; d < 4; ++d) {
                    float a = term_val(ks * 32 + c * 8 + d * 2,     p1, p2, p3);
                    float b = term_val(ks * 32 + c * 8 + d * 2 + 1, p1, p2, p3);
                    ch[d] = pack2bf_fast(a, b);
                }
                sT[c * 64 + lane] = ch;   // row/kq transpose via per-wave LDS
            }

            // --- basis B-fragments from LDS + weight A-fragments from sB ---
#pragma unroll
            for (int q = 0; q < 4; ++q) {
                uint4v bw = sT[kq * 64 + q * 16 + m];
                bf16x8 bfrag = __builtin_bit_cast(bf16x8, bw);
#pragma unroll
                for (int ct = 0; ct < 4; ++ct) {
                    uint4v aw = sB4[(ks * 4 + ct) * 64 + lane];
                    bf16x8 afrag = __builtin_bit_cast(bf16x8, aw);
                    acc[ct][q] = __builtin_amdgcn_mfma_f32_16x16x32_bf16(
                                     afrag, bfrag, acc[ct][q], 0, 0, 0);
                }
            }
        }

        // --- epilogue: per q-block, transpose 16x64 tile via LDS, then
        //     store full 1024B-contiguous spans (rows 4g..4g+3 x 256B).
        //     sO reuses sT's bytes: same-wave DS ordering, no barrier. ---
#pragma unroll
        for (int q = 0; q < 4; ++q) {
#pragma unroll
            for (int ct = 0; ct < 4; ++ct) {
                f32x4* pw = (f32x4*)(sO + m * SOSTRIDE + ct * 16 + kq * 4);
                *pw = acc[ct][q];
            }
#pragma unroll
            for (int g = 0; g < 4; ++g) {
                const int R = 4 * g + kq;
                f32x4 v = *(const f32x4*)(sO + R * SOSTRIDE + m * 4);
                const int orow = rbase + q * 16 + R;
                if (orow < NUM_ROWS) {
                    f32x4* po = (f32x4*)(out + (size_t)orow * 64 + m * 4);
                    *po = v;
                }
            }
        }
    }
}

extern "C" void kernel_launch(void* const* d_in, const int* in_sizes, int n_in,
                              void* d_out, int out_size, void* d_ws, size_t ws_size,
                              hipStream_t stream) {
    const float* x      = (const float*)d_in[0];   // 500000 x 8
    const float* weight = (const float*)d_in[1];   // 64 x 164
    const float* bias   = (const float*)d_in[2];   // 64
    float* out          = (float*)d_out;           // 500000 x 64

    poly_fused_kernel<<<2048, 256, 0, stream>>>(x, weight, bias, out);
}

// Round 10
// 56.146 us; speedup vs baseline: 4.3456x; 4.3456x over previous
//
#include <hip/hip_runtime.h>

#define NUM_ROWS 500000
#define TERMS 164
#define KSTEPS 6                       // 6 * 32 = 192 k-slots (164 terms + bias@164 + pad)
#define NFRAG (KSTEPS * 4)             // 24 weight fragments, each 64 lanes x uint4
#define NITER ((NUM_ROWS + 63) / 64)   // 7813 (last iter: 32 rows)

typedef __attribute__((ext_vector_type(8))) short bf16x8;
typedef __attribute__((ext_vector_type(4))) float f32x4;
typedef __attribute__((ext_vector_type(4))) unsigned int uint4v;

// ---------------------------------------------------------------------------
// Compile-time replica of the reference exponent-table construction
// (verified round 1: term order matches numpy meshgrid/.T/reshape exactly).
// ---------------------------------------------------------------------------
struct ETab { int e[192][8]; int n; };

constexpr ETab make_et() {
    ETab T{};
    for (int i = 0; i < 192; ++i)
        for (int f = 0; f < 8; ++f) T.e[i][f] = 0;
    T.n = 0;
    for (int a = 0; a <= 3; ++a)                       // e7
     for (int b = 0; a + b <= 3; ++b)                  // e6
      for (int c = 0; a + b + c <= 3; ++c)             // e5
       for (int d = 0; a + b + c + d <= 3; ++d)        // e4
        for (int e_ = 0; a + b + c + d + e_ <= 3; ++e_)            // e3
         for (int f_ = 0; a + b + c + d + e_ + f_ <= 3; ++f_)      // e2
          for (int g = 0; a + b + c + d + e_ + f_ + g <= 3; ++g)   // e0
           for (int h = 0; a + b + c + d + e_ + f_ + g + h <= 3; ++h) { // e1
               int s = a + b + c + d + e_ + f_ + g + h;
               if (s >= 1) {
                   T.e[T.n][0] = g;  T.e[T.n][1] = h;
                   T.e[T.n][2] = f_; T.e[T.n][3] = e_;
                   T.e[T.n][4] = d;  T.e[T.n][5] = c;
                   T.e[T.n][6] = b;  T.e[T.n][7] = a;
                   ++T.n;
               }
           }
    return T;
}

static_assert(make_et().n == TERMS, "term count must be 164");
__device__ constexpr ETab ET = make_et();

// Manual RNE float->bf16 pack (verified rounds 1/3/4/6/7). NOTE round-9
// lesson: the v_cvt_pk_bf16_f32 inline-asm variant perturbed regalloc
// (VGPR 68 -> accumulator spill, 8x regression). Keep the plain version.
__device__ __forceinline__ unsigned int pack2bf(float a, float b) {
    unsigned int ua = __float_as_uint(a), ub = __float_as_uint(b);
    ua = ua + 0x7fffu + ((ua >> 16) & 1u);
    ub = ub + 0x7fffu + ((ub >> 16) & 1u);
    return (ua >> 16) | (ub & 0xffff0000u);
}

// Basis term value; t is compile-time constant after unrolling, so ET loads
// and degree branches fold away (<=2 v_mul_f32 per term). Slot 164 is the
// bias slot: basis value 1.0 for every row (weight side carries bias[j]).
__device__ __forceinline__ float term_val(int t, const float (&p1)[8],
                                          const float (&p2)[8],
                                          const float (&p3)[8]) {
    if (t > TERMS) return 0.f;
    if (t == TERMS) return 1.f;
    float v = 1.f;
#pragma unroll
    for (int f = 0; f < 8; ++f) {
        const int d = ET.e[t][f];
        if (d == 1) v *= p1[f];
        else if (d == 2) v *= p2[f];
        else if (d == 3) v *= p3[f];
    }
    return v;
}

// Weight-side value for k-slot t of output column j (runtime t, staging only).
__device__ __forceinline__ float wval(const float* __restrict__ w,
                                      const float* __restrict__ b,
                                      int j, int t) {
    if (t < TERMS) return w[j * TERMS + t];
    if (t == TERMS) return b[j];
    return 0.f;
}

// Pre-pack weight A-fragments into d_ws: fragment p = ks*4+ct, per lane 4
// dwords. Lane (kq,i): A[row = ct*16+i][k = kq*8 + {2dw, 2dw+1}].
__global__ __launch_bounds__(256) void pack_weights_kernel(
        const float* __restrict__ weight, const float* __restrict__ bias,
        unsigned int* __restrict__ wpack) {
    int idx = blockIdx.x * 256 + threadIdx.x;
    if (idx >= NFRAG * 256) return;
    int p    = idx >> 8;
    int lane = (idx >> 2) & 63;
    int dw   = idx & 3;
    int ks = p >> 2, ct = p & 3;
    int kq = lane >> 4;
    int j  = (ct << 4) | (lane & 15);          // output column 0..63
    int t0 = ks * 32 + kq * 8 + dw * 2;
    wpack[idx] = pack2bf(wval(weight, bias, j, t0), wval(weight, bias, j, t0 + 1));
}

// ---------------------------------------------------------------------------
// Round 10 = round 7 (verified 37us) with ONE change: epilogue LDS
// transpose removed; acc stored directly in the D layout
//   out[row rbase+q*16+m][col ct*16+kq*4 + r]  (16B/lane, 256B row stride).
// Rationale: LDS pipe was the #2 aggregate consumer (~12us of 80 b128
// ops/iter); direct stores cut that to 48 and remove the serial epilogue
// LDS round-trip. Traffic-safety evidence: round 1's scalar stores at the
// same 256B stride measured clean 125MB WRITE (L2 merges same-wave
// complementary sectors); rounds 3-6's "amplification" was the (256,4)
// VGPR spill, not the store pattern.
// Round-7 lesson kept: plain __launch_bounds__(256) (no min-occupancy arg).
// ---------------------------------------------------------------------------
__device__ __forceinline__ void poly_body(const float* __restrict__ x,
                                          const uint4v* __restrict__ bsrc,
                                          float* __restrict__ out,
                                          uint4v (&sT)[4][4][64]) {
    const int tid  = threadIdx.x;
    const int lane = tid & 63;
    const int wid  = tid >> 6;
    const int m    = lane & 15;
    const int kq   = lane >> 4;

    const int gw = blockIdx.x * 4 + wid;
    const int nw = gridDim.x * 4;

#pragma unroll 1
    for (int it = gw; it < NITER; it += nw) {
        const int rbase = it * 64;
        const int myrow = rbase + lane;

        float4 xa = {0.f, 0.f, 0.f, 0.f}, xb = {0.f, 0.f, 0.f, 0.f};
        if (myrow < NUM_ROWS) {
            const float4* xp = (const float4*)(x + (size_t)myrow * 8);
            xa = xp[0]; xb = xp[1];
        }
        float p1[8], p2[8], p3[8];
        p1[0] = xa.x; p1[1] = xa.y; p1[2] = xa.z; p1[3] = xa.w;
        p1[4] = xb.x; p1[5] = xb.y; p1[6] = xb.z; p1[7] = xb.w;
#pragma unroll
        for (int f = 0; f < 8; ++f) {
            p2[f] = p1[f] * p1[f];
            p3[f] = p2[f] * p1[f];
        }

        f32x4 acc[4][4];   // [ct][q] — 64 VGPRs, must stay in registers
#pragma unroll
        for (int ct = 0; ct < 4; ++ct)
#pragma unroll
            for (int q = 0; q < 4; ++q)
                acc[ct][q] = (f32x4){0.f, 0.f, 0.f, 0.f};

#pragma unroll
        for (int ks = 0; ks < KSTEPS; ++ks) {
            // --- my row's 32 terms for this ks, packed into 4 uint4 chunks ---
#pragma unroll
            for (int c = 0; c < 4; ++c) {
                uint4v ch;
#pragma unroll
                for (int d = 0; d < 4; ++d) {
                    float a = term_val(ks * 32 + c * 8 + d * 2,     p1, p2, p3);
                    float b = term_val(ks * 32 + c * 8 + d * 2 + 1, p1, p2, p3);
                    ch[d] = pack2bf(a, b);
                }
                sT[wid][c][lane] = ch;   // row/kq transpose via per-wave LDS
            }

            // --- weight A-fragments (uniform across waves; L2-resident) ---
            uint4v aw[4];
#pragma unroll
            for (int ct = 0; ct < 4; ++ct)
                aw[ct] = bsrc[(ks * 4 + ct) * 64 + lane];

            // --- basis B-fragments from LDS + 16 MFMAs ---
#pragma unroll
            for (int q = 0; q < 4; ++q) {
                uint4v bw = sT[wid][kq][q * 16 + m];
                bf16x8 bfrag = __builtin_bit_cast(bf16x8, bw);
#pragma unroll
                for (int ct = 0; ct < 4; ++ct) {
                    bf16x8 afrag = __builtin_bit_cast(bf16x8, aw[ct]);
                    acc[ct][q] = __builtin_amdgcn_mfma_f32_16x16x32_bf16(
                                     afrag, bfrag, acc[ct][q], 0, 0, 0);
                }
            }
        }

        // --- epilogue: direct stores, D layout. Same-wave (ct,kq) chunks
        //     tile complete 256B rows; L2 merges (round-1 evidence). ---
#pragma unroll
        for (int q = 0; q < 4; ++q) {
            const int orow = rbase + q * 16 + m;
            if (orow < NUM_ROWS) {
#pragma unroll
                for (int ct = 0; ct < 4; ++ct) {
                    f32x4* po = (f32x4*)(out + (size_t)orow * 64 + ct * 16 + kq * 4);
                    *po = acc[ct][q];
                }
            }
        }
    }
}

__global__ __launch_bounds__(256) void poly_ws_kernel(
        const float* __restrict__ x, const unsigned int* __restrict__ wpack,
        float* __restrict__ out) {
    __shared__ uint4v sT[4][4][64];   // 16 KiB
    poly_body(x, (const uint4v*)wpack, out, sT);
}

// Fallback if d_ws is too small: stage weight fragments in LDS instead.
__global__ __launch_bounds__(256) void poly_lds_kernel(
        const float* __restrict__ x, const float* __restrict__ weight,
        const float* __restrict__ bias, float* __restrict__ out) {
    __shared__ uint4v sT[4][4][64];          // 16 KiB
    __shared__ unsigned int sB[NFRAG * 256]; // 24 KiB
    const int tid = threadIdx.x;
#pragma unroll 1
    for (int idx = tid; idx < NFRAG * 256; idx += 256) {
        int p = idx >> 8, lane = (idx >> 2) & 63, dw = idx & 3;
        int ks = p >> 2, ct = p & 3, kq = lane >> 4;
        int j  = (ct << 4) | (lane & 15);
        int t0 = ks * 32 + kq * 8 + dw * 2;
        sB[idx] = pack2bf(wval(weight, bias, j, t0), wval(weight, bias, j, t0 + 1));
    }
    __syncthreads();
    poly_body(x, (const uint4v*)sB, out, sT);
}

extern "C" void kernel_launch(void* const* d_in, const int* in_sizes, int n_in,
                              void* d_out, int out_size, void* d_ws, size_t ws_size,
                              hipStream_t stream) {
    const float* x      = (const float*)d_in[0];   // 500000 x 8
    const float* weight = (const float*)d_in[1];   // 64 x 164
    const float* bias   = (const float*)d_in[2];   // 64
    float* out          = (float*)d_out;           // 500000 x 64

    if (ws_size >= (size_t)(NFRAG * 256 * sizeof(unsigned int))) {
        unsigned int* wpack = (unsigned int*)d_ws;
        pack_weights_kernel<<<NFRAG, 256, 0, stream>>>(weight, bias, wpack);
        poly_ws_kernel<<<2048, 256, 0, stream>>>(x, wpack, out);
    } else {
        poly_lds_kernel<<<1024, 256, 0, stream>>>(x, weight, bias, out);
    }
}

// Round 11
// 35.263 us; speedup vs baseline: 6.9192x; 1.5922x over previous
//
#include <hip/hip_runtime.h>
#include <hip/hip_bf16.h>

#define NUM_ROWS 500000
#define TERMS 164
#define KSTEPS 6                       // 6 * 32 = 192 k-slots (164 terms + bias@164 + pad)
#define NFRAG (KSTEPS * 4)             // 24 weight fragments, each 64 lanes x uint4
#define NITER ((NUM_ROWS + 63) / 64)   // 7813 (last iter: 32 rows)
#define SOSTRIDE 68                    // padded row stride (words) for transpose buf

typedef __attribute__((ext_vector_type(8))) short bf16x8;
typedef __attribute__((ext_vector_type(4))) float f32x4;
typedef __attribute__((ext_vector_type(4))) unsigned int uint4v;

// ---------------------------------------------------------------------------
// Compile-time replica of the reference exponent-table construction
// (verified round 1: term order matches numpy meshgrid/.T/reshape exactly).
// ---------------------------------------------------------------------------
struct ETab { int e[192][8]; int n; };

constexpr ETab make_et() {
    ETab T{};
    for (int i = 0; i < 192; ++i)
        for (int f = 0; f < 8; ++f) T.e[i][f] = 0;
    T.n = 0;
    for (int a = 0; a <= 3; ++a)                       // e7
     for (int b = 0; a + b <= 3; ++b)                  // e6
      for (int c = 0; a + b + c <= 3; ++c)             // e5
       for (int d = 0; a + b + c + d <= 3; ++d)        // e4
        for (int e_ = 0; a + b + c + d + e_ <= 3; ++e_)            // e3
         for (int f_ = 0; a + b + c + d + e_ + f_ <= 3; ++f_)      // e2
          for (int g = 0; a + b + c + d + e_ + f_ + g <= 3; ++g)   // e0
           for (int h = 0; a + b + c + d + e_ + f_ + g + h <= 3; ++h) { // e1
               int s = a + b + c + d + e_ + f_ + g + h;
               if (s >= 1) {
                   T.e[T.n][0] = g;  T.e[T.n][1] = h;
                   T.e[T.n][2] = f_; T.e[T.n][3] = e_;
                   T.e[T.n][4] = d;  T.e[T.n][5] = c;
                   T.e[T.n][6] = b;  T.e[T.n][7] = a;
                   ++T.n;
               }
           }
    return T;
}

static_assert(make_et().n == TERMS, "term count must be 164");
__device__ constexpr ETab ET = make_et();

// Manual RNE float->bf16 pack (verified rounds 1/3/4/6/7) — staging path.
__device__ __forceinline__ unsigned int pack2bf(float a, float b) {
    unsigned int ua = __float_as_uint(a), ub = __float_as_uint(b);
    ua = ua + 0x7fffu + ((ua >> 16) & 1u);
    ub = ub + 0x7fffu + ((ub >> 16) & 1u);
    return (ua >> 16) | (ub & 0xffff0000u);
}

// Hot-loop pack: COMPILER-generated v_cvt_pk_bf16_f32 via the HIP intrinsic
// (RNE, numerically identical to pack2bf). Round-9 lesson: the inline-asm
// form pinned operands and broke regalloc (VGPR 68 -> acc spill, 8x slow);
// letting the compiler select the instruction keeps scheduling freedom.
// (__builtin_bit_cast rejected for __hip_bfloat162; __builtin_memcpy is ok.)
__device__ __forceinline__ unsigned int pack2bf_fast(float a, float b) {
    __hip_bfloat162 h = __float22bfloat162_rn(float2{a, b});
    unsigned int r;
    __builtin_memcpy(&r, &h, 4);
    return r;
}

// Basis term value; t is compile-time constant after unrolling, so ET loads
// and degree branches fold away (<=2 v_mul_f32 per term). Slot 164 is the
// bias slot: basis value 1.0 for every row (weight side carries bias[j]).
__device__ __forceinline__ float term_val(int t, const float (&p1)[8],
                                          const float (&p2)[8],
                                          const float (&p3)[8]) {
    if (t > TERMS) return 0.f;
    if (t == TERMS) return 1.f;
    float v = 1.f;
#pragma unroll
    for (int f = 0; f < 8; ++f) {
        const int d = ET.e[t][f];
        if (d == 1) v *= p1[f];
        else if (d == 2) v *= p2[f];
        else if (d == 3) v *= p3[f];
    }
    return v;
}

// Weight-side value for k-slot t of output column j (runtime t, staging only).
__device__ __forceinline__ float wval(const float* __restrict__ w,
                                      const float* __restrict__ b,
                                      int j, int t) {
    if (t < TERMS) return w[j * TERMS + t];
    if (t == TERMS) return b[j];
    return 0.f;
}

// Pre-pack weight A-fragments into d_ws: fragment p = ks*4+ct, per lane 4
// dwords. Lane (kq,i): A[row = ct*16+i][k = kq*8 + {2dw, 2dw+1}].
__global__ __launch_bounds__(256) void pack_weights_kernel(
        const float* __restrict__ weight, const float* __restrict__ bias,
        unsigned int* __restrict__ wpack) {
    int idx = blockIdx.x * 256 + threadIdx.x;
    if (idx >= NFRAG * 256) return;
    int p    = idx >> 8;
    int lane = (idx >> 2) & 63;
    int dw   = idx & 3;
    int ks = p >> 2, ct = p & 3;
    int kq = lane >> 4;
    int j  = (ct << 4) | (lane & 15);          // output column 0..63
    int t0 = ks * 32 + kq * 8 + dw * 2;
    wpack[idx] = pack2bf(wval(weight, bias, j, t0), wval(weight, bias, j, t0 + 1));
}

// ---------------------------------------------------------------------------
// CHAMPION STRUCTURE (round 7, 37.0us) + compiler-cvt_pk packing.
// Compute: A=weights, B=basis (verified absmax 0.25).
//   acc[ct][q][r] = out[row rbase+q*16+m][col ct*16+kq*4+r]
// Round-7 lesson: plain __launch_bounds__(256) — (256,4) made the allocator
// pick 64 VGPRs vs ~125 live -> accumulator spill (rounds 3-6 "phantom
// write amplification").
// Round-10 lesson: direct strided f32x4 stores cost +19us vs this LDS
// transpose epilogue (64B sectors vs 1024B contiguous) — keep transpose.
// ---------------------------------------------------------------------------
__device__ __forceinline__ void poly_body(const float* __restrict__ x,
                                          const uint4v* __restrict__ bsrc,
                                          float* __restrict__ out,
                                          uint4v (&sT)[4][4][64],
                                          f32x4 (&sO4)[4][16 * SOSTRIDE / 4]) {
    const int tid  = threadIdx.x;
    const int lane = tid & 63;
    const int wid  = tid >> 6;
    const int m    = lane & 15;
    const int kq   = lane >> 4;

    const int gw = blockIdx.x * 4 + wid;
    const int nw = gridDim.x * 4;

    float* sO = (float*)&sO4[wid][0];

#pragma unroll 1
    for (int it = gw; it < NITER; it += nw) {
        const int rbase = it * 64;
        const int myrow = rbase + lane;

        float4 xa = {0.f, 0.f, 0.f, 0.f}, xb = {0.f, 0.f, 0.f, 0.f};
        if (myrow < NUM_ROWS) {
            const float4* xp = (const float4*)(x + (size_t)myrow * 8);
            xa = xp[0]; xb = xp[1];
        }
        float p1[8], p2[8], p3[8];
        p1[0] = xa.x; p1[1] = xa.y; p1[2] = xa.z; p1[3] = xa.w;
        p1[4] = xb.x; p1[5] = xb.y; p1[6] = xb.z; p1[7] = xb.w;
#pragma unroll
        for (int f = 0; f < 8; ++f) {
            p2[f] = p1[f] * p1[f];
            p3[f] = p2[f] * p1[f];
        }

        f32x4 acc[4][4];   // [ct][q] — 64 VGPRs, must stay in registers
#pragma unroll
        for (int ct = 0; ct < 4; ++ct)
#pragma unroll
            for (int q = 0; q < 4; ++q)
                acc[ct][q] = (f32x4){0.f, 0.f, 0.f, 0.f};

#pragma unroll
        for (int ks = 0; ks < KSTEPS; ++ks) {
            // --- my row's 32 terms for this ks, packed into 4 uint4 chunks ---
#pragma unroll
            for (int c = 0; c < 4; ++c) {
                uint4v ch;
#pragma unroll
                for (int d = 0; d < 4; ++d) {
                    float a = term_val(ks * 32 + c * 8 + d * 2,     p1, p2, p3);
                    float b = term_val(ks * 32 + c * 8 + d * 2 + 1, p1, p2, p3);
                    ch[d] = pack2bf_fast(a, b);
                }
                sT[wid][c][lane] = ch;   // row/kq transpose via per-wave LDS
            }

            // --- weight A-fragments (uniform across waves; L2-resident) ---
            uint4v aw[4];
#pragma unroll
            for (int ct = 0; ct < 4; ++ct)
                aw[ct] = bsrc[(ks * 4 + ct) * 64 + lane];

            // --- basis B-fragments from LDS + 16 MFMAs ---
#pragma unroll
            for (int q = 0; q < 4; ++q) {
                uint4v bw = sT[wid][kq][q * 16 + m];
                bf16x8 bfrag = __builtin_bit_cast(bf16x8, bw);
#pragma unroll
                for (int ct = 0; ct < 4; ++ct) {
                    bf16x8 afrag = __builtin_bit_cast(bf16x8, aw[ct]);
                    acc[ct][q] = __builtin_amdgcn_mfma_f32_16x16x32_bf16(
                                     afrag, bfrag, acc[ct][q], 0, 0, 0);
                }
            }
        }

        // --- epilogue: per q-block, transpose 16x64 tile via LDS, then
        //     store full 256B rows (1024B contiguous per instruction) ---
#pragma unroll
        for (int q = 0; q < 4; ++q) {
#pragma unroll
            for (int ct = 0; ct < 4; ++ct) {
                f32x4* pw = (f32x4*)(sO + m * SOSTRIDE + ct * 16 + kq * 4);
                *pw = acc[ct][q];
            }
#pragma unroll
            for (int g = 0; g < 4; ++g) {
                const int R = 4 * g + kq;
                f32x4 v = *(const f32x4*)(sO + R * SOSTRIDE + m * 4);
                const int orow = rbase + q * 16 + R;
                if (orow < NUM_ROWS) {
                    f32x4* po = (f32x4*)(out + (size_t)orow * 64 + m * 4);
                    *po = v;
                }
            }
        }
    }
}

__global__ __launch_bounds__(256) void poly_ws_kernel(
        const float* __restrict__ x, const unsigned int* __restrict__ wpack,
        float* __restrict__ out) {
    __shared__ uint4v sT[4][4][64];                 // 16 KiB
    __shared__ f32x4  sO4[4][16 * SOSTRIDE / 4];    // 17 KiB
    poly_body(x, (const uint4v*)wpack, out, sT, sO4);
}

// Fallback if d_ws is too small: stage weight fragments in LDS instead.
__global__ __launch_bounds__(256) void poly_lds_kernel(
        const float* __restrict__ x, const float* __restrict__ weight,
        const float* __restrict__ bias, float* __restrict__ out) {
    __shared__ uint4v sT[4][4][64];                 // 16 KiB
    __shared__ f32x4  sO4[4][16 * SOSTRIDE / 4];    // 17 KiB
    __shared__ unsigned int sB[NFRAG * 256];        // 24 KiB
    const int tid = threadIdx.x;
#pragma unroll 1
    for (int idx = tid; idx < NFRAG * 256; idx += 256) {
        int p = idx >> 8, lane = (idx >> 2) & 63, dw = idx & 3;
        int ks = p >> 2, ct = p & 3, kq = lane >> 4;
        int j  = (ct << 4) | (lane & 15);
        int t0 = ks * 32 + kq * 8 + dw * 2;
        sB[idx] = pack2bf(wval(weight, bias, j, t0), wval(weight, bias, j, t0 + 1));
    }
    __syncthreads();
    poly_body(x, (const uint4v*)sB, out, sT, sO4);
}

extern "C" void kernel_launch(void* const* d_in, const int* in_sizes, int n_in,
                              void* d_out, int out_size, void* d_ws, size_t ws_size,
                              hipStream_t stream) {
    const float* x      = (const float*)d_in[0];   // 500000 x 8
    const float* weight = (const float*)d_in[1];   // 64 x 164
    const float* bias   = (const float*)d_in[2];   // 64
    float* out          = (float*)d_out;           // 500000 x 64

    if (ws_size >= (size_t)(NFRAG * 256 * sizeof(unsigned int))) {
        unsigned int* wpack = (unsigned int*)d_ws;
        pack_weights_kernel<<<NFRAG, 256, 0, stream>>>(weight, bias, wpack);
        poly_ws_kernel<<<2048, 256, 0, stream>>>(x, wpack, out);
    } else {
        poly_lds_kernel<<<1024, 256, 0, stream>>>(x, weight, bias, out);
    }
}

// Round 14
// 34.971 us; speedup vs baseline: 6.9769x; 1.0083x over previous
//
#include <hip/hip_runtime.h>
#include <hip/hip_bf16.h>

#define NUM_ROWS 500000
#define TERMS 164
#define KSTEPS 6                       // 6 * 32 = 192 k-slots (164 terms + bias@164 + pad)
#define NFRAG (KSTEPS * 4)             // 24 weight fragments, each 64 lanes x uint4
#define NITER ((NUM_ROWS + 63) / 64)   // 7813 (last iter: 32 rows)
#define SOSTRIDE 68                    // padded row stride (words) for transpose buf

typedef __attribute__((ext_vector_type(8))) short bf16x8;
typedef __attribute__((ext_vector_type(4))) float f32x4;
typedef __attribute__((ext_vector_type(4))) unsigned int uint4v;

// ---------------------------------------------------------------------------
// ROUND 14 = VERBATIM ROUND-11 CHAMPION (35.3us, absmax 0.25; this exact
// structure passed rounds 7/10/11 and re-validated after graph replay).
// Fusion of the pack kernel (rounds 9/12/13) is permanently abandoned: the
// per-wave LDS exchange is cross-lane, but compiler alias analysis is
// per-thread, so aggressive codegen can legally sink LDS writes past reads
// of other lanes' data. The two-dispatch form's codegen is verified good.
// Lessons carried:
//  - plain __launch_bounds__(256): (256,4) forced 64 VGPRs -> acc spill
//    (rounds 3-6 phantom "write amplification", round 7 3.4x win)
//  - epilogue LDS transpose for 1024B-contiguous stores (round 10 A/B: +19us
//    for direct strided f32x4 stores)
//  - intrinsic cvt_pk (__float22bfloat162_rn), NOT inline asm (round 9:
//    asm operand pinning -> VGPR 68 -> 8x regression; round 11: -1.8us)
// ---------------------------------------------------------------------------

struct ETab { int e[192][8]; int n; };

constexpr ETab make_et() {
    ETab T{};
    for (int i = 0; i < 192; ++i)
        for (int f = 0; f < 8; ++f) T.e[i][f] = 0;
    T.n = 0;
    for (int a = 0; a <= 3; ++a)                       // e7
     for (int b = 0; a + b <= 3; ++b)                  // e6
      for (int c = 0; a + b + c <= 3; ++c)             // e5
       for (int d = 0; a + b + c + d <= 3; ++d)        // e4
        for (int e_ = 0; a + b + c + d + e_ <= 3; ++e_)            // e3
         for (int f_ = 0; a + b + c + d + e_ + f_ <= 3; ++f_)      // e2
          for (int g = 0; a + b + c + d + e_ + f_ + g <= 3; ++g)   // e0
           for (int h = 0; a + b + c + d + e_ + f_ + g + h <= 3; ++h) { // e1
               int s = a + b + c + d + e_ + f_ + g + h;
               if (s >= 1) {
                   T.e[T.n][0] = g;  T.e[T.n][1] = h;
                   T.e[T.n][2] = f_; T.e[T.n][3] = e_;
                   T.e[T.n][4] = d;  T.e[T.n][5] = c;
                   T.e[T.n][6] = b;  T.e[T.n][7] = a;
                   ++T.n;
               }
           }
    return T;
}

static_assert(make_et().n == TERMS, "term count must be 164");
__device__ constexpr ETab ET = make_et();

// Manual RNE float->bf16 pack (verified rounds 1-11) — staging path.
__device__ __forceinline__ unsigned int pack2bf(float a, float b) {
    unsigned int ua = __float_as_uint(a), ub = __float_as_uint(b);
    ua = ua + 0x7fffu + ((ua >> 16) & 1u);
    ub = ub + 0x7fffu + ((ub >> 16) & 1u);
    return (ua >> 16) | (ub & 0xffff0000u);
}

// Hot-loop pack: compiler-generated v_cvt_pk_bf16_f32 via the HIP intrinsic.
__device__ __forceinline__ unsigned int pack2bf_fast(float a, float b) {
    __hip_bfloat162 h = __float22bfloat162_rn(float2{a, b});
    unsigned int r;
    __builtin_memcpy(&r, &h, 4);
    return r;
}

// Basis term value; t is compile-time constant after unrolling, so ET loads
// and degree branches fold away (<=2 v_mul_f32 per term). Slot 164 is the
// bias slot: basis value 1.0 for every row (weight side carries bias[j]).
__device__ __forceinline__ float term_val(int t, const float (&p1)[8],
                                          const float (&p2)[8],
                                          const float (&p3)[8]) {
    if (t > TERMS) return 0.f;
    if (t == TERMS) return 1.f;
    float v = 1.f;
#pragma unroll
    for (int f = 0; f < 8; ++f) {
        const int d = ET.e[t][f];
        if (d == 1) v *= p1[f];
        else if (d == 2) v *= p2[f];
        else if (d == 3) v *= p3[f];
    }
    return v;
}

// Weight-side value for k-slot t of output column j (runtime t, staging only).
__device__ __forceinline__ float wval(const float* __restrict__ w,
                                      const float* __restrict__ b,
                                      int j, int t) {
    if (t < TERMS) return w[j * TERMS + t];
    if (t == TERMS) return b[j];
    return 0.f;
}

// Pre-pack weight A-fragments into d_ws: fragment p = ks*4+ct, per lane 4
// dwords. Lane (kq,i): A[row = ct*16+i][k = kq*8 + {2dw, 2dw+1}].
__global__ __launch_bounds__(256) void pack_weights_kernel(
        const float* __restrict__ weight, const float* __restrict__ bias,
        unsigned int* __restrict__ wpack) {
    int idx = blockIdx.x * 256 + threadIdx.x;
    if (idx >= NFRAG * 256) return;
    int p    = idx >> 8;
    int lane = (idx >> 2) & 63;
    int dw   = idx & 3;
    int ks = p >> 2, ct = p & 3;
    int kq = lane >> 4;
    int j  = (ct << 4) | (lane & 15);          // output column 0..63
    int t0 = ks * 32 + kq * 8 + dw * 2;
    wpack[idx] = pack2bf(wval(weight, bias, j, t0), wval(weight, bias, j, t0 + 1));
}

// ---------------------------------------------------------------------------
// Champion body: compute A=weights, B=basis (verified absmax 0.25).
//   acc[ct][q][r] = out[row rbase+q*16+m][col ct*16+kq*4+r]
// ---------------------------------------------------------------------------
__device__ __forceinline__ void poly_body(const float* __restrict__ x,
                                          const uint4v* __restrict__ bsrc,
                                          float* __restrict__ out,
                                          uint4v (&sT)[4][4][64],
                                          f32x4 (&sO4)[4][16 * SOSTRIDE / 4]) {
    const int tid  = threadIdx.x;
    const int lane = tid & 63;
    const int wid  = tid >> 6;
    const int m    = lane & 15;
    const int kq   = lane >> 4;

    const int gw = blockIdx.x * 4 + wid;
    const int nw = gridDim.x * 4;

    float* sO = (float*)&sO4[wid][0];

#pragma unroll 1
    for (int it = gw; it < NITER; it += nw) {
        const int rbase = it * 64;
        const int myrow = rbase + lane;

        float4 xa = {0.f, 0.f, 0.f, 0.f}, xb = {0.f, 0.f, 0.f, 0.f};
        if (myrow < NUM_ROWS) {
            const float4* xp = (const float4*)(x + (size_t)myrow * 8);
            xa = xp[0]; xb = xp[1];
        }
        float p1[8], p2[8], p3[8];
        p1[0] = xa.x; p1[1] = xa.y; p1[2] = xa.z; p1[3] = xa.w;
        p1[4] = xb.x; p1[5] = xb.y; p1[6] = xb.z; p1[7] = xb.w;
#pragma unroll
        for (int f = 0; f < 8; ++f) {
            p2[f] = p1[f] * p1[f];
            p3[f] = p2[f] * p1[f];
        }

        f32x4 acc[4][4];   // [ct][q] — 64 VGPRs, must stay in registers
#pragma unroll
        for (int ct = 0; ct < 4; ++ct)
#pragma unroll
            for (int q = 0; q < 4; ++q)
                acc[ct][q] = (f32x4){0.f, 0.f, 0.f, 0.f};

#pragma unroll
        for (int ks = 0; ks < KSTEPS; ++ks) {
            // --- my row's 32 terms for this ks, packed into 4 uint4 chunks ---
#pragma unroll
            for (int c = 0; c < 4; ++c) {
                uint4v ch;
#pragma unroll
                for (int d = 0; d < 4; ++d) {
                    float a = term_val(ks * 32 + c * 8 + d * 2,     p1, p2, p3);
                    float b = term_val(ks * 32 + c * 8 + d * 2 + 1, p1, p2, p3);
                    ch[d] = pack2bf_fast(a, b);
                }
                sT[wid][c][lane] = ch;   // row/kq transpose via per-wave LDS
            }

            // --- weight A-fragments (uniform across waves; L2-resident) ---
            uint4v aw[4];
#pragma unroll
            for (int ct = 0; ct < 4; ++ct)
                aw[ct] = bsrc[(ks * 4 + ct) * 64 + lane];

            // --- basis B-fragments from LDS + 16 MFMAs ---
#pragma unroll
            for (int q = 0; q < 4; ++q) {
                uint4v bw = sT[wid][kq][q * 16 + m];
                bf16x8 bfrag = __builtin_bit_cast(bf16x8, bw);
#pragma unroll
                for (int ct = 0; ct < 4; ++ct) {
                    bf16x8 afrag = __builtin_bit_cast(bf16x8, aw[ct]);
                    acc[ct][q] = __builtin_amdgcn_mfma_f32_16x16x32_bf16(
                                     afrag, bfrag, acc[ct][q], 0, 0, 0);
                }
            }
        }

        // --- epilogue: per q-block, transpose 16x64 tile via LDS, then
        //     store full 256B rows (1024B contiguous per instruction) ---
#pragma unroll
        for (int q = 0; q < 4; ++q) {
#pragma unroll
            for (int ct = 0; ct < 4; ++ct) {
                f32x4* pw = (f32x4*)(sO + m * SOSTRIDE + ct * 16 + kq * 4);
                *pw = acc[ct][q];
            }
#pragma unroll
            for (int g = 0; g < 4; ++g) {
                const int R = 4 * g + kq;
                f32x4 v = *(const f32x4*)(sO + R * SOSTRIDE + m * 4);
                const int orow = rbase + q * 16 + R;
                if (orow < NUM_ROWS) {
                    f32x4* po = (f32x4*)(out + (size_t)orow * 64 + m * 4);
                    *po = v;
                }
            }
        }
    }
}

__global__ __launch_bounds__(256) void poly_ws_kernel(
        const float* __restrict__ x, const unsigned int* __restrict__ wpack,
        float* __restrict__ out) {
    __shared__ uint4v sT[4][4][64];                 // 16 KiB
    __shared__ f32x4  sO4[4][16 * SOSTRIDE / 4];    // 17 KiB
    poly_body(x, (const uint4v*)wpack, out, sT, sO4);
}

// Fallback if d_ws is too small: stage weight fragments in LDS instead.
__global__ __launch_bounds__(256) void poly_lds_kernel(
        const float* __restrict__ x, const float* __restrict__ weight,
        const float* __restrict__ bias, float* __restrict__ out) {
    __shared__ uint4v sT[4][4][64];                 // 16 KiB
    __shared__ f32x4  sO4[4][16 * SOSTRIDE / 4];    // 17 KiB
    __shared__ unsigned int sB[NFRAG * 256];        // 24 KiB
    const int tid = threadIdx.x;
#pragma unroll 1
    for (int idx = tid; idx < NFRAG * 256; idx += 256) {
        int p = idx >> 8, lane = (idx >> 2) & 63, dw = idx & 3;
        int ks = p >> 2, ct = p & 3, kq = lane >> 4;
        int j  = (ct << 4) | (lane & 15);
        int t0 = ks * 32 + kq * 8 + dw * 2;
        sB[idx] = pack2bf(wval(weight, bias, j, t0), wval(weight, bias, j, t0 + 1));
    }
    __syncthreads();
    poly_body(x, (const uint4v*)sB, out, sT, sO4);
}

extern "C" void kernel_launch(void* const* d_in, const int* in_sizes, int n_in,
                              void* d_out, int out_size, void* d_ws, size_t ws_size,
                              hipStream_t stream) {
    const float* x      = (const float*)d_in[0];   // 500000 x 8
    const float* weight = (const float*)d_in[1];   // 64 x 164
    const float* bias   = (const float*)d_in[2];   // 64
    float* out          = (float*)d_out;           // 500000 x 64

    if (ws_size >= (size_t)(NFRAG * 256 * sizeof(unsigned int))) {
        unsigned int* wpack = (unsigned int*)d_ws;
        pack_weights_kernel<<<NFRAG, 256, 0, stream>>>(weight, bias, wpack);
        poly_ws_kernel<<<2048, 256, 0, stream>>>(x, wpack, out);
    } else {
        poly_lds_kernel<<<1024, 256, 0, stream>>>(x, weight, bias, out);
    }
}